// Round 8
// baseline (20.393 us; speedup 1.0000x reference)
//
#include <hip/hip_runtime.h>

#define GX 512
#define NF 32
#define XD 1024
#define NPIX (XD * XD)

#define ROWB2 8256                 // 129 cells * 64 B (f16)
#define STAGEB (2 * ROWB2)         // 16512 B raw corner staging
#define SCRB 2048                  // per-wave h1 scratch: 2 slots * 1 KB
#define LDSBYTES (STAGEB + 4 * SCRB)

typedef _Float16 half8 __attribute__((ext_vector_type(8)));
typedef __fp16  fp16x2 __attribute__((ext_vector_type(2)));
typedef float  floatx4 __attribute__((ext_vector_type(4)));

union PkU { fp16x2 h; unsigned u; };
union FragU { half8 h; uint4 u4; unsigned u[4]; };

__device__ __forceinline__ unsigned pkrtz(float a, float b) {
    PkU x; x.h = __builtin_amdgcn_cvt_pkrtz(a, b); return x.u;
}

// Bilinear folded into MFMA: lerp weights are {0.25,0.75} by parity, so corner
// weights come from {1,3,9}/16. Pixel tiles = 16 same-parity columns -> corner
// weights are tile-uniform -> layer1 = 4 chained MFMAs with pre-scaled W1
// A-frags over RAW staged cells. The 4 corner B-frags are shared by all 8
// chains (2 row-par x 2 col-par x 2 jt) of a 32-column group.
__global__ __launch_bounds__(256, 4) void t3d_main(
    const float* __restrict__ data,
    const float* __restrict__ W1, const float* __restrict__ b1,
    const float* __restrict__ W2, const float* __restrict__ b2,
    const float* __restrict__ W3, const float* __restrict__ b3,
    float* __restrict__ out)
{
    __shared__ uint4 lds4[LDSBYTES / 16];
    unsigned char* lds = (unsigned char*)lds4;

    const int tid  = threadIdx.x;
    const int wid  = tid >> 6;
    const int lane = tid & 63;
    const int c = lane & 15, g = lane >> 4;

    // XCD swizzle: 2048 wgs, 8 XCDs, 256 contiguous per XCD (bijective)
    const int bid = blockIdx.x;
    const int wg  = (bid & 7) * 256 + (bid >> 3);
    const int rp  = wg >> 2;          // row pair: image rows 2rp, 2rp+1
    const int cbk = wg & 3;           // 256-pixel column block
    const int XB  = 128 * cbk;        // first grid cell of block
    const int y0r = rp;
    const int y1r = min(rp + 1, GX - 1);

    // ---- cooperative staging: 2 grid rows x 129 cells, f32 -> f16 ----------
    const int cl = tid >> 3, fl = tid & 7;     // 8 lanes per cell
#pragma unroll
    for (int r = 0; r < 2; ++r) {
        const float* rowp = data + (size_t)(r ? y1r : y0r) * (GX * NF);
        unsigned char* rb = lds + r * ROWB2;
#pragma unroll
        for (int k = 0; k < 4; ++k) {
            const int cell = 32 * k + cl;
            const float4 v = *(const float4*)(rowp + (XB + cell) * NF + 4 * fl);
            uint2 u = { pkrtz(v.x, v.y), pkrtz(v.z, v.w) };
            const int ch = (fl >> 1) ^ (cell & 3);
            *(uint2*)(rb + cell * 64 + ch * 16 + (fl & 1) * 8) = u;
        }
    }
    if (tid < 16) {   // boundary cell 128 (clamped at grid edge)
        const int r = tid >> 3, L = tid & 7;
        const float* rowp = data + (size_t)(r ? y1r : y0r) * (GX * NF);
        const int col = min(XB + 128, GX - 1);
        const float4 v = *(const float4*)(rowp + col * NF + 4 * L);
        uint2 u = { pkrtz(v.x, v.y), pkrtz(v.z, v.w) };
        *(uint2*)(lds + r * ROWB2 + 128 * 64 + (L >> 1) * 16 + (L & 1) * 8) = u;
    }

    // ---- pre-scaled A-frags: {9,3,1}/16 * W1, plus W2 frags + biases -------
    FragU A9[2], A3[2], A1f[2], aw2[2];
    floatx4 bia1[2], bia2[2], w3f[2];
#pragma unroll
    for (int jt = 0; jt < 2; ++jt) {
#pragma unroll
        for (int w = 0; w < 4; ++w) {
            const float whi = W1[(8*g + 2*w    ) * NF + 16*jt + c];
            const float wlo = W1[(8*g + 2*w + 1) * NF + 16*jt + c];
            A9[jt].u[w]  = pkrtz(0.5625f * whi, 0.5625f * wlo);
            A3[jt].u[w]  = pkrtz(0.1875f * whi, 0.1875f * wlo);
            A1f[jt].u[w] = pkrtz(0.0625f * whi, 0.0625f * wlo);
            aw2[jt].u[w] = pkrtz(W2[(8*g+2*w)*NF + 16*jt + c], W2[(8*g+2*w+1)*NF + 16*jt + c]);
        }
        bia1[jt] = ((const floatx4*)b1)[4*jt + g];
        bia2[jt] = ((const floatx4*)b2)[4*jt + g];
        w3f[jt]  = ((const floatx4*)W3)[4*jt + g];
    }

    __syncthreads();

    const int swc = c & 3;
    unsigned char* scr = lds + STAGEB + wid * SCRB;
    float ss[8];

    // PT body: layer1 chain (4 MFMAs x 2 jt) -> relu/pack -> scratch roundtrip
    // -> layer2 (2 MFMAs) -> layer3 partial. F* = A-frag per corner.
#define PT_BODY(CG, PR, TP, FT0, FT1, FB0, FB1)                                   \
    {                                                                             \
        floatx4 d0 = bia1[0], d1 = bia1[1];                                       \
        d0 = __builtin_amdgcn_mfma_f32_16x16x32_f16(FT0[0].h, cT0.h, d0, 0,0,0);  \
        d1 = __builtin_amdgcn_mfma_f32_16x16x32_f16(FT0[1].h, cT0.h, d1, 0,0,0);  \
        d0 = __builtin_amdgcn_mfma_f32_16x16x32_f16(FT1[0].h, cT1.h, d0, 0,0,0);  \
        d1 = __builtin_amdgcn_mfma_f32_16x16x32_f16(FT1[1].h, cT1.h, d1, 0,0,0);  \
        d0 = __builtin_amdgcn_mfma_f32_16x16x32_f16(FB0[0].h, cB0.h, d0, 0,0,0);  \
        d1 = __builtin_amdgcn_mfma_f32_16x16x32_f16(FB0[1].h, cB0.h, d1, 0,0,0);  \
        d0 = __builtin_amdgcn_mfma_f32_16x16x32_f16(FB1[0].h, cB1.h, d0, 0,0,0);  \
        d1 = __builtin_amdgcn_mfma_f32_16x16x32_f16(FB1[1].h, cB1.h, d1, 0,0,0);  \
        uint2 v0 = { pkrtz(fmaxf(d0[0],0.f), fmaxf(d0[1],0.f)),                   \
                     pkrtz(fmaxf(d0[2],0.f), fmaxf(d0[3],0.f)) };                 \
        uint2 v1 = { pkrtz(fmaxf(d1[0],0.f), fmaxf(d1[1],0.f)),                   \
                     pkrtz(fmaxf(d1[2],0.f), fmaxf(d1[3],0.f)) };                 \
        unsigned char* scw = scr + (TP) * 1024;                                   \
        *(uint2*)(scw + c*64 + (g&1)*8 + 16*((g>>1)^swc))       = v0;             \
        *(uint2*)(scw + c*64 + (g&1)*8 + 16*(((g>>1)+2)^swc))   = v1;             \
        FragU h1f; h1f.u4 = *(const uint4*)(scw + c*64 + 16*(g^swc));             \
        floatx4 e0 = __builtin_amdgcn_mfma_f32_16x16x32_f16(aw2[0].h, h1f.h, bia2[0], 0,0,0); \
        floatx4 e1 = __builtin_amdgcn_mfma_f32_16x16x32_f16(aw2[1].h, h1f.h, bia2[1], 0,0,0); \
        float t = 0.0f;                                                           \
        _Pragma("unroll")                                                         \
        for (int r = 0; r < 4; ++r) {                                             \
            t = fmaf(fmaxf(e0[r], 0.0f), w3f[0][r], t);                           \
            t = fmaf(fmaxf(e1[r], 0.0f), w3f[1][r], t);                           \
        }                                                                         \
        ss[(PR)*4 + (CG)*2 + (TP)] = t;                                           \
    }

#pragma unroll
    for (int cg = 0; cg < 2; ++cg) {
        // 4 shared corner B-frags for this 32-column group
        const int o0 = 32 * wid + 16 * cg + c;
        const int a0 = o0 * 64 + 16 * (g ^ (o0 & 3));
        const int a1 = (o0 + 1) * 64 + 16 * (g ^ ((o0 + 1) & 3));
        FragU cT0, cT1, cB0, cB1;
        cT0.u4 = *(const uint4*)(lds + a0);
        cT1.u4 = *(const uint4*)(lds + a1);
        cB0.u4 = *(const uint4*)(lds + ROWB2 + a0);
        cB1.u4 = *(const uint4*)(lds + ROWB2 + a1);

        // corner weights (wA,wB,wC,wD)*16: pr0/tp0: 9,3,3,1 | pr0/tp1: 3,9,1,3
        //                                  pr1/tp0: 3,1,9,3 | pr1/tp1: 1,3,3,9
        PT_BODY(cg, 0, 0, A9,  A3,  A3,  A1f)
        PT_BODY(cg, 0, 1, A3,  A9,  A1f, A3)
        PT_BODY(cg, 1, 0, A3,  A1f, A9,  A3)
        PT_BODY(cg, 1, 1, A1f, A3,  A3,  A9)
    }
#undef PT_BODY

    // ---- batched reduction: xor32 stage (dual-slot), then xor16 stage ------
    const bool lo = (lane < 32);
    float tt[4];
#pragma unroll
    for (int k = 0; k < 4; ++k) {
        const float x  = lo ? ss[4 + k] : ss[k];     // send what partner needs
        const float rv = __shfl_xor(x, 32, 64);
        tt[k] = (lo ? ss[k] : ss[4 + k]) + rv;
    }
    const bool go = (g & 1);
    const float u0 = go ? tt[0] : tt[2];
    const float r0 = __shfl_xor(u0, 16, 64);
    const float fin0 = (go ? tt[2] : tt[0]) + r0;
    const float u1 = go ? tt[1] : tt[3];
    const float r1 = __shfl_xor(u1, 16, 64);
    const float fin1 = (go ? tt[3] : tt[1]) + r1;

    // lane (g,c): pts {2g,2g+1} = (pr=g>>1, cg=g&1, tp=0/1) -> cols 2c,2c+1
    const float b3v = b3[0];
    const int orow = 2 * rp + (g >> 1);
    const int ocol = 256 * cbk + 64 * wid + 32 * (g & 1) + 2 * c;
    float2 o2 = { fin0 + b3v, fin1 + b3v };
    *(float2*)(out + (size_t)orow * XD + ocol) = o2;
}

extern "C" void kernel_launch(void* const* d_in, const int* in_sizes, int n_in,
                              void* d_out, int out_size, void* d_ws, size_t ws_size,
                              hipStream_t stream) {
    // inputs: z, data, W1, b1, W2, b2, W3, b3, x0, y0, x1, y1, lerp_weights
    const float* data = (const float*)d_in[1];
    const float* W1   = (const float*)d_in[2];
    const float* b1   = (const float*)d_in[3];
    const float* W2   = (const float*)d_in[4];
    const float* b2   = (const float*)d_in[5];
    const float* W3   = (const float*)d_in[6];
    const float* b3   = (const float*)d_in[7];
    float* out = (float*)d_out;
    (void)d_ws; (void)ws_size;

    const int blocks = NPIX / 512;   // 2048 = 512 row-pairs x 4 column blocks
    hipLaunchKernelGGL(t3d_main, dim3(blocks), dim3(256), 0, stream,
                       data, W1, b1, W2, b2, W3, b3, out);
}

// Round 9
// 17.670 us; speedup vs baseline: 1.1541x; 1.1541x over previous
//
#include <hip/hip_runtime.h>

#define GX 512
#define NF 32
#define XD 1024
#define NPIX (XD * XD)

#define CELLB 64                 // f16 cell = 32 feats * 2 B
#define NCELL 33                 // 32 cells + boundary
#define RROWB (NCELL * CELLB)    // 2112 B per staged row
#define RAWB  (5 * RROWB)        // 10560 B raw corners (5 grid rows)
#define GOFF  RAWB
#define LDSBYTES (2 * RAWB)      // + 10560 B for G

typedef _Float16 half8 __attribute__((ext_vector_type(8)));
typedef __fp16  fp16x2 __attribute__((ext_vector_type(2)));
typedef float  floatx4 __attribute__((ext_vector_type(4)));

union PkU { fp16x2 h; unsigned u; };
union FragU { half8 h; uint4 u4; fp16x2 p[4]; unsigned u[4]; };

__device__ __forceinline__ unsigned pkrtz(float a, float b) {
    PkU x; x.h = __builtin_amdgcn_cvt_pkrtz(a, b); return x.u;
}
__device__ __forceinline__ fp16x2 sp2(float w) {
    __fp16 h = (__fp16)w; fp16x2 v = {h, h}; return v;
}
__device__ __forceinline__ unsigned relu_pk(unsigned s) {
    unsigned r;
    asm("v_pk_max_f16 %0, %1, 0" : "=v"(r) : "v"(s));
    return r;
}

// G-factorization: h1_pre = interp(W1^T*cell + b1) because bilinear weights
// sum to 1. Block = 8 image rows x 64 cols -> 5 grid rows x 33 cells staged
// once (fetch ratio 1.25x vs 2x). G computed in-block by MFMA, stored f16 in
// LDS with swizzle sigma(cell)=(cell>>1)&3: G-compute reads 2-way banked,
// pixel interp reads conflict-free (hand-derived). Interp output IS the
// layer-2 B-frag -> no h1 LDS roundtrip at all.
__global__ __launch_bounds__(256, 4) void t3d_main(
    const float* __restrict__ data,
    const float* __restrict__ W1, const float* __restrict__ b1,
    const float* __restrict__ W2, const float* __restrict__ b2,
    const float* __restrict__ W3, const float* __restrict__ b3,
    float* __restrict__ out)
{
    __shared__ uint4 lds4[LDSBYTES / 16];
    unsigned char* raw = (unsigned char*)lds4;
    unsigned char* Gb  = raw + GOFF;

    const int tid  = threadIdx.x;
    const int wid  = tid >> 6;
    const int lane = tid & 63;
    const int c = lane & 15, g = lane >> 4;

    // XCD swizzle: 2048 wgs, 8 XCDs, 256 contiguous per XCD (bijective)
    const int bid = blockIdx.x;
    const int wg  = (bid & 7) * 256 + (bid >> 3);
    const int RB  = wg >> 4;          // row-block: image rows 8RB..8RB+7
    const int cbk = wg & 15;          // 64-pixel column block
    const int XB  = 32 * cbk;         // first grid cell
    const int YB  = 4 * RB;           // first grid row

    // ---- cooperative staging: 5 grid rows x 33 cells, f32 -> f16 -----------
    const int cl = tid >> 3, fl = tid & 7;   // 8 lanes per cell, 32 cells
#pragma unroll
    for (int rr = 0; rr < 5; ++rr) {
        const int y = min(YB + rr, GX - 1);
        const float4 v = *(const float4*)(data + (size_t)y * (GX * NF) + (XB + cl) * NF + 4 * fl);
        uint2 u = { pkrtz(v.x, v.y), pkrtz(v.z, v.w) };
        *(uint2*)(raw + rr * RROWB + cl * CELLB
                  + (((fl >> 1) ^ ((cl >> 1) & 3)) << 4) + ((fl & 1) << 3)) = u;
    }
    if (tid < 40) {   // boundary cell 32 (clamped at grid edge)
        const int rr = tid >> 3, L = tid & 7;
        const int y = min(YB + rr, GX - 1);
        const int col = min(XB + 32, GX - 1);
        const float4 v = *(const float4*)(data + (size_t)y * (GX * NF) + col * NF + 4 * L);
        uint2 u = { pkrtz(v.x, v.y), pkrtz(v.z, v.w) };
        *(uint2*)(raw + rr * RROWB + 32 * CELLB + ((L >> 1) << 4) + ((L & 1) << 3)) = u;
    }

    // ---- weight fragments (L2-resident; overlaps staging latency) ----------
    FragU aw1[2], aw2[2]; floatx4 bia1[2], bia2[2], w3f[2];
#pragma unroll
    for (int jt = 0; jt < 2; ++jt) {
#pragma unroll
        for (int w = 0; w < 4; ++w) {
            aw1[jt].u[w] = pkrtz(W1[(8*g+2*w)*NF + 16*jt + c], W1[(8*g+2*w+1)*NF + 16*jt + c]);
            aw2[jt].u[w] = pkrtz(W2[(8*g+2*w)*NF + 16*jt + c], W2[(8*g+2*w+1)*NF + 16*jt + c]);
        }
        bia1[jt] = ((const floatx4*)b1)[4*jt + g];
        bia2[jt] = ((const floatx4*)b2)[4*jt + g];
        w3f[jt]  = ((const floatx4*)W3)[4*jt + g];
    }

    __syncthreads();

    // ---- G-compute: 15 tiles (5 rows x {0-15,16-31,17-32}), wave-strided ---
#pragma unroll
    for (int k = 0; k < 4; ++k) {
        const int T = wid + 4 * k;
        if (T < 15) {
            const int rr  = T / 3;
            const int seg = T - 3 * rr;
            const int ct0 = (seg < 2) ? (seg << 4) : 17;
            const int cell = ct0 + c;
            FragU B;
            B.u4 = *(const uint4*)(raw + rr * RROWB + cell * CELLB
                                   + ((g ^ ((cell >> 1) & 3)) << 4));
            floatx4 d0 = __builtin_amdgcn_mfma_f32_16x16x32_f16(aw1[0].h, B.h, bia1[0], 0, 0, 0);
            floatx4 d1 = __builtin_amdgcn_mfma_f32_16x16x32_f16(aw1[1].h, B.h, bia1[1], 0, 0, 0);
            uint2 u0 = { pkrtz(d0[0], d0[1]), pkrtz(d0[2], d0[3]) };
            uint2 u1 = { pkrtz(d1[0], d1[1]), pkrtz(d1[2], d1[3]) };
            const int sg = (cell >> 1) & 3;
            unsigned char* gc = Gb + rr * RROWB + cell * CELLB + ((g & 1) << 3);
            *(uint2*)(gc + ((((g >> 1)    ) ^ sg) << 4)) = u0;   // feats 4g..4g+3
            *(uint2*)(gc + ((((g >> 1) + 2) ^ sg) << 4)) = u1;   // feats 16+4g..
        }
    }

    __syncthreads();

    // ---- pixel loop: wave = image rows {2wid, 2wid+1} x 64 cols ------------
    const float w0p = (c & 1) ? 0.75f : 0.25f;
    const float m0  = 1.0f - w0p;
    // par = image-row parity: par0 w1=0.25, par1 w1=0.75
    const fp16x2 WA[2] = { sp2(m0  * 0.75f), sp2(m0  * 0.25f) };
    const fp16x2 WB[2] = { sp2(w0p * 0.75f), sp2(w0p * 0.25f) };
    const fp16x2 WC[2] = { sp2(m0  * 0.25f), sp2(m0  * 0.75f) };
    const fp16x2 WD[2] = { sp2(w0p * 0.25f), sp2(w0p * 0.75f) };

    unsigned char* Gt = Gb + wid * RROWB;        // y0 = 4RB + wid
    unsigned char* Gm = Gb + (wid + 1) * RROWB;  // y1

    float ss[8];
#pragma unroll
    for (int ct = 0; ct < 4; ++ct) {
        const int o0 = 8 * ct + (c >> 1);
        const int o1 = o0 + 1;                   // boundary cell is pre-clamped
        const int a0 = o0 * CELLB + ((g ^ ((o0 >> 1) & 3)) << 4);
        const int a1 = o1 * CELLB + ((g ^ ((o1 >> 1) & 3)) << 4);
        FragU cT0, cT1, cB0, cB1;
        cT0.u4 = *(const uint4*)(Gt + a0);
        cT1.u4 = *(const uint4*)(Gt + a1);
        cB0.u4 = *(const uint4*)(Gm + a0);
        cB1.u4 = *(const uint4*)(Gm + a1);
#pragma unroll
        for (int par = 0; par < 2; ++par) {
            FragU f;
#pragma unroll
            for (int w = 0; w < 4; ++w) {
                fp16x2 t0 = cT0.p[w] * WA[par] + cT1.p[w] * WB[par];
                fp16x2 t1 = cB0.p[w] * WC[par] + cB1.p[w] * WD[par];
                PkU s; s.h = t0 + t1;
                f.u[w] = relu_pk(s.u);           // h1 = relu(interp(G))
            }
            // layer 2: f is already the B-frag (feats 8g..8g+7 of pixel col)
            floatx4 e0 = __builtin_amdgcn_mfma_f32_16x16x32_f16(aw2[0].h, f.h, bia2[0], 0, 0, 0);
            floatx4 e1 = __builtin_amdgcn_mfma_f32_16x16x32_f16(aw2[1].h, f.h, bia2[1], 0, 0, 0);
            float t = 0.0f;
#pragma unroll
            for (int r = 0; r < 4; ++r) {
                t = fmaf(fmaxf(e0[r], 0.0f), w3f[0][r], t);
                t = fmaf(fmaxf(e1[r], 0.0f), w3f[1][r], t);
            }
            ss[par * 4 + ct] = t;
        }
    }

    // ---- batched reduction over g-groups (round-8 verified pattern) --------
    const bool lo = (lane < 32);
    float tt[4];
#pragma unroll
    for (int k = 0; k < 4; ++k) {
        const float x  = lo ? ss[4 + k] : ss[k];
        const float rv = __shfl_xor(x, 32, 64);
        tt[k] = (lo ? ss[k] : ss[4 + k]) + rv;
    }
    const bool go = (g & 1);
    const float u0 = go ? tt[0] : tt[2];
    const float r0 = __shfl_xor(u0, 16, 64);
    const float fin0 = (go ? tt[2] : tt[0]) + r0;
    const float u1 = go ? tt[1] : tt[3];
    const float r1 = __shfl_xor(u1, 16, 64);
    const float fin1 = (go ? tt[3] : tt[1]) + r1;

    // lane (g,c): row 2wid+(g>>1), cols 32(g&1)+c and +16
    const float b3v = b3[0];
    const int orow = 8 * RB + 2 * wid + (g >> 1);
    const int ocol = 64 * cbk + 32 * (g & 1) + c;
    out[(size_t)orow * XD + ocol]      = fin0 + b3v;
    out[(size_t)orow * XD + ocol + 16] = fin1 + b3v;
}

extern "C" void kernel_launch(void* const* d_in, const int* in_sizes, int n_in,
                              void* d_out, int out_size, void* d_ws, size_t ws_size,
                              hipStream_t stream) {
    // inputs: z, data, W1, b1, W2, b2, W3, b3, x0, y0, x1, y1, lerp_weights
    const float* data = (const float*)d_in[1];
    const float* W1   = (const float*)d_in[2];
    const float* b1   = (const float*)d_in[3];
    const float* W2   = (const float*)d_in[4];
    const float* b2   = (const float*)d_in[5];
    const float* W3   = (const float*)d_in[6];
    const float* b3   = (const float*)d_in[7];
    float* out = (float*)d_out;
    (void)d_ws; (void)ws_size;

    const int blocks = NPIX / 512;   // 2048 = 128 row-blocks x 16 col-blocks
    hipLaunchKernelGGL(t3d_main, dim3(blocks), dim3(256), 0, stream,
                       data, W1, b1, W2, b2, W3, b3, out);
}

// Round 11
// 17.472 us; speedup vs baseline: 1.1671x; 1.0113x over previous
//
#include <hip/hip_runtime.h>

#define GX 512
#define NF 32
#define XD 1024
#define NPIX (XD * XD)

#define CELLB 64                 // f16 cell = 32 feats * 2 B
#define NCELL 33                 // 32 cells + boundary
#define RROWB (NCELL * CELLB)    // 2112 B per staged/G row
#define RAWB  (5 * RROWB)        // 10560 B raw corners (5 grid rows)
#define LDSBYTES (RAWB + 8 * RROWB)   // + per-wave G: 4 waves x 2 rows

typedef _Float16 half8 __attribute__((ext_vector_type(8)));
typedef __fp16  fp16x2 __attribute__((ext_vector_type(2)));
typedef float  floatx4 __attribute__((ext_vector_type(4)));

union PkU { fp16x2 h; unsigned u; };
union FragU { half8 h; uint4 u4; fp16x2 p[4]; unsigned u[4]; };

__device__ __forceinline__ unsigned pkrtz(float a, float b) {
    PkU x; x.h = __builtin_amdgcn_cvt_pkrtz(a, b); return x.u;
}
__device__ __forceinline__ fp16x2 sp2(float w) {
    __fp16 h = (__fp16)w; fp16x2 v = {h, h}; return v;
}
__device__ __forceinline__ unsigned relu_pk(unsigned s) {
    unsigned r;
    asm("v_pk_max_f16 %0, %1, 0" : "=v"(r) : "v"(s));
    return r;
}

// Round-9 verified G-factorization (h1_pre = interp(G), G = W1^T*cell + b1),
// restructured: G-compute is PER-WAVE (each wave builds its own G rows
// {wid, wid+1} into a private LDS region; adjacent waves duplicate one row's
// MFMAs -- free at 3% MfmaUtil). Removes the second barrier entirely:
// stage -> barrier -> per-wave G -> pixel loop. All layouts/swizzles are the
// round-9 verified formulas; round-10's packed boundary tile reverted.
__global__ __launch_bounds__(256, 4) void t3d_main(
    const float* __restrict__ data,
    const float* __restrict__ W1, const float* __restrict__ b1,
    const float* __restrict__ W2, const float* __restrict__ b2,
    const float* __restrict__ W3, const float* __restrict__ b3,
    float* __restrict__ out)
{
    __shared__ uint4 lds4[LDSBYTES / 16];
    unsigned char* raw = (unsigned char*)lds4;
    unsigned char* Gb  = raw + RAWB;

    const int tid  = threadIdx.x;
    const int wid  = tid >> 6;
    const int lane = tid & 63;
    const int c = lane & 15, g = lane >> 4;

    // XCD swizzle: 2048 wgs, 8 XCDs, 256 contiguous per XCD (bijective)
    const int bid = blockIdx.x;
    const int wg  = (bid & 7) * 256 + (bid >> 3);
    const int RB  = wg >> 4;          // row-block: image rows 8RB..8RB+7
    const int cbk = wg & 15;          // 64-pixel column block
    const int XB  = 32 * cbk;         // first grid cell
    const int YB  = 4 * RB;           // first grid row

    // ---- cooperative staging: 5 grid rows x 33 cells, f32 -> f16 -----------
    const int cl = tid >> 3, fl = tid & 7;   // 8 lanes per cell, 32 cells
#pragma unroll
    for (int rr = 0; rr < 5; ++rr) {
        const int y = min(YB + rr, GX - 1);
        const float4 v = *(const float4*)(data + (size_t)y * (GX * NF) + (XB + cl) * NF + 4 * fl);
        uint2 u = { pkrtz(v.x, v.y), pkrtz(v.z, v.w) };
        *(uint2*)(raw + rr * RROWB + cl * CELLB
                  + (((fl >> 1) ^ ((cl >> 1) & 3)) << 4) + ((fl & 1) << 3)) = u;
    }
    if (tid < 40) {   // boundary cell 32 (clamped at grid edge)
        const int rr = tid >> 3, L = tid & 7;
        const int y = min(YB + rr, GX - 1);
        const int col = min(XB + 32, GX - 1);
        const float4 v = *(const float4*)(data + (size_t)y * (GX * NF) + col * NF + 4 * L);
        uint2 u = { pkrtz(v.x, v.y), pkrtz(v.z, v.w) };
        *(uint2*)(raw + rr * RROWB + 32 * CELLB + ((L >> 1) << 4) + ((L & 1) << 3)) = u;
    }

    // ---- weight fragments (L2-resident; overlaps staging latency) ----------
    FragU aw1[2], aw2[2]; floatx4 bia1[2], bia2[2], w3f[2];
#pragma unroll
    for (int jt = 0; jt < 2; ++jt) {
#pragma unroll
        for (int w = 0; w < 4; ++w) {
            aw1[jt].u[w] = pkrtz(W1[(8*g+2*w)*NF + 16*jt + c], W1[(8*g+2*w+1)*NF + 16*jt + c]);
            aw2[jt].u[w] = pkrtz(W2[(8*g+2*w)*NF + 16*jt + c], W2[(8*g+2*w+1)*NF + 16*jt + c]);
        }
        bia1[jt] = ((const floatx4*)b1)[4*jt + g];
        bia2[jt] = ((const floatx4*)b2)[4*jt + g];
        w3f[jt]  = ((const floatx4*)W3)[4*jt + g];
    }

    __syncthreads();   // the ONLY barrier: raw staging is cross-wave

    // ---- per-wave G-compute: rows {wid, wid+1} x segs {0-15,16-31,17-32} ---
    unsigned char* Gw = Gb + wid * (2 * RROWB);
#pragma unroll
    for (int rl = 0; rl < 2; ++rl) {
        const int rr = wid + rl;
#pragma unroll
        for (int seg = 0; seg < 3; ++seg) {
            const int ct0  = (seg < 2) ? (seg << 4) : 17;
            const int cell = ct0 + c;
            FragU B;
            B.u4 = *(const uint4*)(raw + rr * RROWB + cell * CELLB
                                   + ((g ^ ((cell >> 1) & 3)) << 4));
            floatx4 d0 = __builtin_amdgcn_mfma_f32_16x16x32_f16(aw1[0].h, B.h, bia1[0], 0, 0, 0);
            floatx4 d1 = __builtin_amdgcn_mfma_f32_16x16x32_f16(aw1[1].h, B.h, bia1[1], 0, 0, 0);
            uint2 u0 = { pkrtz(d0[0], d0[1]), pkrtz(d0[2], d0[3]) };
            uint2 u1 = { pkrtz(d1[0], d1[1]), pkrtz(d1[2], d1[3]) };
            const int sg = (cell >> 1) & 3;
            unsigned char* gc = Gw + rl * RROWB + cell * CELLB + ((g & 1) << 3);
            *(uint2*)(gc + ((((g >> 1)    ) ^ sg) << 4)) = u0;   // feats 4g..4g+3
            *(uint2*)(gc + ((((g >> 1) + 2) ^ sg) << 4)) = u1;   // feats 16+4g..
        }
    }

    // ---- pixel loop: wave = image rows {2wid, 2wid+1} x 64 cols ------------
    // (reads only this wave's own G -> same-wave in-order DS, no barrier)
    const float w0p = (c & 1) ? 0.75f : 0.25f;
    const float m0  = 1.0f - w0p;
    // par = image-row parity: par0 w1=0.25, par1 w1=0.75
    const fp16x2 WA[2] = { sp2(m0  * 0.75f), sp2(m0  * 0.25f) };
    const fp16x2 WB[2] = { sp2(w0p * 0.75f), sp2(w0p * 0.25f) };
    const fp16x2 WC[2] = { sp2(m0  * 0.25f), sp2(m0  * 0.75f) };
    const fp16x2 WD[2] = { sp2(w0p * 0.25f), sp2(w0p * 0.75f) };

    unsigned char* Gt = Gw;              // grid row wid   (y0)
    unsigned char* Gm = Gw + RROWB;      // grid row wid+1 (y1)

    float ss[8];
#pragma unroll
    for (int ct = 0; ct < 4; ++ct) {
        const int o0 = 8 * ct + (c >> 1);
        const int o1 = o0 + 1;                   // boundary cell pre-clamped
        const int a0 = o0 * CELLB + ((g ^ ((o0 >> 1) & 3)) << 4);
        const int a1 = o1 * CELLB + ((g ^ ((o1 >> 1) & 3)) << 4);
        FragU cT0, cT1, cB0, cB1;
        cT0.u4 = *(const uint4*)(Gt + a0);
        cT1.u4 = *(const uint4*)(Gt + a1);
        cB0.u4 = *(const uint4*)(Gm + a0);
        cB1.u4 = *(const uint4*)(Gm + a1);
#pragma unroll
        for (int par = 0; par < 2; ++par) {
            FragU f;
#pragma unroll
            for (int w = 0; w < 4; ++w) {
                fp16x2 t0 = cT0.p[w] * WA[par] + cT1.p[w] * WB[par];
                fp16x2 t1 = cB0.p[w] * WC[par] + cB1.p[w] * WD[par];
                PkU s; s.h = t0 + t1;
                f.u[w] = relu_pk(s.u);           // h1 = relu(interp(G))
            }
            floatx4 e0 = __builtin_amdgcn_mfma_f32_16x16x32_f16(aw2[0].h, f.h, bia2[0], 0, 0, 0);
            floatx4 e1 = __builtin_amdgcn_mfma_f32_16x16x32_f16(aw2[1].h, f.h, bia2[1], 0, 0, 0);
            float t = 0.0f;
#pragma unroll
            for (int r = 0; r < 4; ++r) {
                t = fmaf(fmaxf(e0[r], 0.0f), w3f[0][r], t);
                t = fmaf(fmaxf(e1[r], 0.0f), w3f[1][r], t);
            }
            ss[par * 4 + ct] = t;
        }
    }

    // ---- batched reduction over g-groups (verified pattern) ----------------
    const bool lo = (lane < 32);
    float tt[4];
#pragma unroll
    for (int k = 0; k < 4; ++k) {
        const float x  = lo ? ss[4 + k] : ss[k];
        const float rv = __shfl_xor(x, 32, 64);
        tt[k] = (lo ? ss[k] : ss[4 + k]) + rv;
    }
    const bool go = (g & 1);
    const float u0 = go ? tt[0] : tt[2];
    const float r0 = __shfl_xor(u0, 16, 64);
    const float fin0 = (go ? tt[2] : tt[0]) + r0;
    const float u1 = go ? tt[1] : tt[3];
    const float r1 = __shfl_xor(u1, 16, 64);
    const float fin1 = (go ? tt[3] : tt[1]) + r1;

    // lane (g,c): row 2wid+(g>>1), cols 32(g&1)+c and +16
    const float b3v = b3[0];
    const int orow = 8 * RB + 2 * wid + (g >> 1);
    const int ocol = 64 * cbk + 32 * (g & 1) + c;
    out[(size_t)orow * XD + ocol]      = fin0 + b3v;
    out[(size_t)orow * XD + ocol + 16] = fin1 + b3v;
}

extern "C" void kernel_launch(void* const* d_in, const int* in_sizes, int n_in,
                              void* d_out, int out_size, void* d_ws, size_t ws_size,
                              hipStream_t stream) {
    // inputs: z, data, W1, b1, W2, b2, W3, b3, x0, y0, x1, y1, lerp_weights
    const float* data = (const float*)d_in[1];
    const float* W1   = (const float*)d_in[2];
    const float* b1   = (const float*)d_in[3];
    const float* W2   = (const float*)d_in[4];
    const float* b2   = (const float*)d_in[5];
    const float* W3   = (const float*)d_in[6];
    const float* b3   = (const float*)d_in[7];
    float* out = (float*)d_out;
    (void)d_ws; (void)ws_size;

    const int blocks = NPIX / 512;   // 2048 = 128 row-blocks x 16 col-blocks
    hipLaunchKernelGGL(t3d_main, dim3(blocks), dim3(256), 0, stream,
                       data, W1, b1, W2, b2, W3, b3, out);
}